// Round 1
// baseline (1626.954 us; speedup 1.0000x reference)
//
#include <hip/hip_runtime.h>
#include <hip/hip_bf16.h>
#include <stdint.h>

#define N_NODES 100000
#define HDIM 128
#define ECH 64
#define NEDGE 1600000

typedef float f4 __attribute__((ext_vector_type(4)));
typedef short bf8 __attribute__((ext_vector_type(8)));

__device__ __forceinline__ unsigned short f2bf(float f) {
  union { float f; unsigned u; } c; c.f = f;
  return (unsigned short)((c.u + 0x7FFFu + ((c.u >> 16) & 1u)) >> 16);
}

// shifted softplus: log(1+e^z) - log(2)
__device__ __forceinline__ float sspf(float z) {
  const float LN2 = 0.6931471805599453f;
  float t = __expf(z);
  float r = __logf(1.0f + t) - LN2;
  return (z > 15.0f) ? (z - LN2) : r;
}

// Pack B matrix [K][128] (row-major f32, K = nkb*32) into bf16 MFMA
// B-fragments in LDS. Fragment f = t*nkb + kb (t = 16-col tile). Lane L's
// 8 elements: B[kb*32 + (L>>4)*8 + j][t*16 + (L&15)], j = 0..7, stored
// contiguously at dst[(f*64+L)*8] so the hot-loop read is a coalesced
// conflict-free ds_read_b128.
__device__ __forceinline__ void pack_bfrags(const float* __restrict__ w,
                                            short* __restrict__ dst, int nkb,
                                            int tid, int nthreads) {
  int total = 8 * nkb * 64;
  for (int i = tid; i < total; i += nthreads) {
    int L = i & 63;
    int f = i >> 6;
    int kb = f % nkb;
    int t = f / nkb;
    int col = t * 16 + (L & 15);
    int k0 = kb * 32 + ((L >> 4) << 3);
    bf8 vv;
#pragma unroll
    for (int j = 0; j < 8; ++j)
      vv[j] = (short)f2bf(w[(size_t)(k0 + j) * HDIM + col]);
    *(bf8*)(dst + (size_t)i * 8) = vv;
  }
}

// ---------------- kernel 1: v = x @ lin1_w + lin1_b ----------------
__global__ __launch_bounds__(256, 2) void k_pre(const float* __restrict__ x,
                                                const float* __restrict__ w1,
                                                const float* __restrict__ b1,
                                                float* __restrict__ v) {
  __shared__ __attribute__((aligned(16))) short bfr[32 * 64 * 8];  // 32 KB
  __shared__ float bias[HDIM];
  int tid = threadIdx.x;
  pack_bfrags(w1, bfr, 4, tid, 256);
  if (tid < HDIM) bias[tid] = b1[tid];
  __syncthreads();

  int L = tid & 63;
  int m = L & 15, q = L >> 4;
  int gw = (blockIdx.x * 256 + tid) >> 6;
  int nw = (gridDim.x * 256) >> 6;
  const int ntile = N_NODES / 16;
  for (int tile = gw; tile < ntile; tile += nw) {
    int row0 = tile << 4;
    const float* xr = x + (size_t)(row0 + m) * HDIM;
    bf8 a[4];
#pragma unroll
    for (int kb = 0; kb < 4; ++kb) {
      int k0 = kb * 32 + q * 8;
      f4 lo = *(const f4*)(xr + k0);
      f4 hi = *(const f4*)(xr + k0 + 4);
      bf8 t8;
#pragma unroll
      for (int j = 0; j < 4; ++j) {
        t8[j] = (short)f2bf(lo[j]);
        t8[4 + j] = (short)f2bf(hi[j]);
      }
      a[kb] = t8;
    }
    f4 acc[8];
#pragma unroll
    for (int t = 0; t < 8; ++t) acc[t] = (f4){0.f, 0.f, 0.f, 0.f};
#pragma unroll
    for (int kb = 0; kb < 4; ++kb)
#pragma unroll
      for (int t = 0; t < 8; ++t)
        acc[t] = __builtin_amdgcn_mfma_f32_16x16x32_bf16(
            a[kb], *(const bf8*)(bfr + ((t * 4 + kb) * 64 + L) * 8), acc[t], 0,
            0, 0);
#pragma unroll
    for (int t = 0; t < 8; ++t) {
      int col = t * 16 + m;
      float bb = bias[col];
      float* vout = v + (size_t)row0 * HDIM + col;
#pragma unroll
      for (int r = 0; r < 4; ++r) vout[(q * 4 + r) * HDIM] = acc[t][r] + bb;
    }
  }
}

// ------- kernel 2: edge filter + gather + modulate + scatter-add -------
__global__ __launch_bounds__(256, 2) void k_edge(
    const float* __restrict__ ea, const float* __restrict__ ew,
    const float* __restrict__ cf1, const float* __restrict__ cf2,
    const float* __restrict__ cb2, const int* __restrict__ ei,
    const float* __restrict__ v, float* __restrict__ agg) {
  __shared__ __attribute__((aligned(16))) short b1f[16 * 64 * 8];  // 16 KB
  __shared__ __attribute__((aligned(16))) short b2f[32 * 64 * 8];  // 32 KB
  __shared__ __attribute__((aligned(16))) short scr[4][16 * 136];  // 17 KB
  __shared__ float bias2[HDIM];
  int tid = threadIdx.x;
  pack_bfrags(cf1, b1f, 2, tid, 256);
  pack_bfrags(cf2, b2f, 4, tid, 256);
  if (tid < HDIM) bias2[tid] = cb2[tid];
  __syncthreads();

  // edge_index may arrive as int64 (reference dtype) or int32 (harness doc).
  // int64 little-endian with values < 2^31 -> every odd int32 word is 0.
  int stride64 = ((ei[1] | ei[3] | ei[5] | ei[7] | ei[9] | ei[11]) == 0) ? 2 : 1;

  int wave = tid >> 6, L = tid & 63;
  int m = L & 15, q = L >> 4;
  short* wsc = &scr[wave][0];
  int gw = (blockIdx.x * 256 + tid) >> 6;
  int nw = (gridDim.x * 256) >> 6;
  const int ntile = NEDGE / 16;
  for (int tile = gw; tile < ntile; tile += nw) {
    int e0 = tile << 4;
    // ---- GEMM1: z1 = edge_attr @ cf1_w  (K = 64) ----
    const float* ar = ea + (size_t)(e0 + m) * ECH;
    bf8 a[2];
#pragma unroll
    for (int kb = 0; kb < 2; ++kb) {
      int k0 = kb * 32 + q * 8;
      f4 lo = *(const f4*)(ar + k0);
      f4 hi = *(const f4*)(ar + k0 + 4);
      bf8 t8;
#pragma unroll
      for (int j = 0; j < 4; ++j) {
        t8[j] = (short)f2bf(lo[j]);
        t8[4 + j] = (short)f2bf(hi[j]);
      }
      a[kb] = t8;
    }
    f4 acc[8];
#pragma unroll
    for (int t = 0; t < 8; ++t) acc[t] = (f4){0.f, 0.f, 0.f, 0.f};
#pragma unroll
    for (int kb = 0; kb < 2; ++kb)
#pragma unroll
      for (int t = 0; t < 8; ++t)
        acc[t] = __builtin_amdgcn_mfma_f32_16x16x32_bf16(
            a[kb], *(const bf8*)(b1f + ((t * 2 + kb) * 64 + L) * 8), acc[t], 0,
            0, 0);
    // W1 = ssp(z1) -> per-wave LDS scratch (C-layout write, padded stride 136)
#pragma unroll
    for (int t = 0; t < 8; ++t) {
      int col = t * 16 + m;
#pragma unroll
      for (int r = 0; r < 4; ++r)
        wsc[(q * 4 + r) * 136 + col] = (short)f2bf(sspf(acc[t][r]));
    }
    // ---- GEMM2: z2 = W1 @ cf2_w  (K = 128); A-frags from scratch ----
    bf8 a2[4];
#pragma unroll
    for (int kb = 0; kb < 4; ++kb)
      a2[kb] = *(const bf8*)(wsc + m * 136 + kb * 32 + q * 8);
#pragma unroll
    for (int t = 0; t < 8; ++t) acc[t] = (f4){0.f, 0.f, 0.f, 0.f};
#pragma unroll
    for (int kb = 0; kb < 4; ++kb)
#pragma unroll
      for (int t = 0; t < 8; ++t)
        acc[t] = __builtin_amdgcn_mfma_f32_16x16x32_bf16(
            a2[kb], *(const bf8*)(b2f + ((t * 4 + kb) * 64 + L) * 8), acc[t], 0,
            0, 0);
    // ---- epilogue: W2 = ssp(z2+b); msg = v[src]*W2*ew; atomic agg[dst] ----
#pragma unroll
    for (int r = 0; r < 4; ++r) {
      int erow = e0 + q * 4 + r;
      int srcn = ei[(size_t)erow * stride64];
      int dstn = ei[((size_t)NEDGE + erow) * stride64];
      float w_e = ew[erow];
      const float* vrow = v + (size_t)srcn * HDIM;
      float* arow = agg + (size_t)dstn * HDIM;
#pragma unroll
      for (int t = 0; t < 8; ++t) {
        int col = t * 16 + m;
        float w2 = sspf(acc[t][r] + bias2[col]);
        __hip_atomic_fetch_add(arow + col, vrow[col] * w2 * w_e,
                               __ATOMIC_RELAXED, __HIP_MEMORY_SCOPE_AGENT);
      }
    }
  }
}

// --- kernel 3: out = x + ssp(agg @ lin2 + b2) @ lin3 + b3 ---
__global__ __launch_bounds__(256) void k_post(
    const float* __restrict__ agg, const float* __restrict__ w2,
    const float* __restrict__ b2, const float* __restrict__ w3,
    const float* __restrict__ b3, const float* __restrict__ x,
    float* __restrict__ out) {
  __shared__ __attribute__((aligned(16))) short f2l[32 * 64 * 8];  // 32 KB
  __shared__ __attribute__((aligned(16))) short f3l[32 * 64 * 8];  // 32 KB
  __shared__ __attribute__((aligned(16))) short scr[4][16 * 136];  // 17 KB
  __shared__ float bias2[HDIM], bias3[HDIM];
  int tid = threadIdx.x;
  pack_bfrags(w2, f2l, 4, tid, 256);
  pack_bfrags(w3, f3l, 4, tid, 256);
  if (tid < HDIM) {
    bias2[tid] = b2[tid];
    bias3[tid] = b3[tid];
  }
  __syncthreads();

  int wave = tid >> 6, L = tid & 63;
  int m = L & 15, q = L >> 4;
  short* wsc = &scr[wave][0];
  int gw = (blockIdx.x * 256 + tid) >> 6;
  int nw = (gridDim.x * 256) >> 6;
  const int ntile = N_NODES / 16;
  for (int tile = gw; tile < ntile; tile += nw) {
    int row0 = tile << 4;
    const float* gr = agg + (size_t)(row0 + m) * HDIM;
    bf8 a[4];
#pragma unroll
    for (int kb = 0; kb < 4; ++kb) {
      int k0 = kb * 32 + q * 8;
      f4 lo = *(const f4*)(gr + k0);
      f4 hi = *(const f4*)(gr + k0 + 4);
      bf8 t8;
#pragma unroll
      for (int j = 0; j < 4; ++j) {
        t8[j] = (short)f2bf(lo[j]);
        t8[4 + j] = (short)f2bf(hi[j]);
      }
      a[kb] = t8;
    }
    f4 acc[8];
#pragma unroll
    for (int t = 0; t < 8; ++t) acc[t] = (f4){0.f, 0.f, 0.f, 0.f};
#pragma unroll
    for (int kb = 0; kb < 4; ++kb)
#pragma unroll
      for (int t = 0; t < 8; ++t)
        acc[t] = __builtin_amdgcn_mfma_f32_16x16x32_bf16(
            a[kb], *(const bf8*)(f2l + ((t * 4 + kb) * 64 + L) * 8), acc[t], 0,
            0, 0);
    // h = ssp(z + b2) -> scratch
#pragma unroll
    for (int t = 0; t < 8; ++t) {
      int col = t * 16 + m;
      float bb = bias2[col];
#pragma unroll
      for (int r = 0; r < 4; ++r)
        wsc[(q * 4 + r) * 136 + col] = (short)f2bf(sspf(acc[t][r] + bb));
    }
    bf8 a2[4];
#pragma unroll
    for (int kb = 0; kb < 4; ++kb)
      a2[kb] = *(const bf8*)(wsc + m * 136 + kb * 32 + q * 8);
#pragma unroll
    for (int t = 0; t < 8; ++t) acc[t] = (f4){0.f, 0.f, 0.f, 0.f};
#pragma unroll
    for (int kb = 0; kb < 4; ++kb)
#pragma unroll
      for (int t = 0; t < 8; ++t)
        acc[t] = __builtin_amdgcn_mfma_f32_16x16x32_bf16(
            a2[kb], *(const bf8*)(f3l + ((t * 4 + kb) * 64 + L) * 8), acc[t], 0,
            0, 0);
#pragma unroll
    for (int t = 0; t < 8; ++t) {
      int col = t * 16 + m;
      float bb = bias3[col];
      const float* xr = x + (size_t)row0 * HDIM + col;
      float* orow = out + (size_t)row0 * HDIM + col;
#pragma unroll
      for (int r = 0; r < 4; ++r) {
        int ro = (q * 4 + r) * HDIM;
        orow[ro] = xr[ro] + acc[t][r] + bb;
      }
    }
  }
}

extern "C" void kernel_launch(void* const* d_in, const int* in_sizes, int n_in,
                              void* d_out, int out_size, void* d_ws,
                              size_t ws_size, hipStream_t stream) {
  const float* x = (const float*)d_in[0];
  const float* ea = (const float*)d_in[1];
  const float* ew = (const float*)d_in[2];
  const float* l1w = (const float*)d_in[3];
  const float* l1b = (const float*)d_in[4];
  const float* c1w = (const float*)d_in[5];
  const float* c2w = (const float*)d_in[6];
  const float* c2b = (const float*)d_in[7];
  const float* l2w = (const float*)d_in[8];
  const float* l2b = (const float*)d_in[9];
  const float* l3w = (const float*)d_in[10];
  const float* l3b = (const float*)d_in[11];
  const int* ei = (const int*)d_in[12];
  float* out = (float*)d_out;

  float* v = (float*)d_ws;                      // [N, 128] f32, 51.2 MB
  float* agg = v + (size_t)N_NODES * HDIM;      // [N, 128] f32, 51.2 MB

  hipMemsetAsync(agg, 0, (size_t)N_NODES * HDIM * sizeof(float), stream);
  k_pre<<<512, 256, 0, stream>>>(x, l1w, l1b, v);
  k_edge<<<512, 256, 0, stream>>>(ea, ew, c1w, c2w, c2b, ei, v, agg);
  k_post<<<256, 256, 0, stream>>>(agg, l2w, l2b, l3w, l3b, x, out);
}

// Round 2
// 1165.642 us; speedup vs baseline: 1.3958x; 1.3958x over previous
//
#include <hip/hip_runtime.h>
#include <hip/hip_bf16.h>
#include <stdint.h>

#define N_NODES 100000
#define HDIM 128
#define ECH 64
#define NEDGE 1600000

typedef float f4 __attribute__((ext_vector_type(4)));
typedef short bf8 __attribute__((ext_vector_type(8)));
typedef _Float16 h2 __attribute__((ext_vector_type(2)));
typedef _Float16 h8 __attribute__((ext_vector_type(8)));

__device__ __forceinline__ unsigned short f2bf(float f) {
  union { float f; unsigned u; } c; c.f = f;
  return (unsigned short)((c.u + 0x7FFFu + ((c.u >> 16) & 1u)) >> 16);
}
__device__ __forceinline__ float bf2f(unsigned short b) {
  union { unsigned u; float f; } c; c.u = ((unsigned)b) << 16;
  return c.f;
}

// shifted softplus: log(1+e^z) - log(2)
__device__ __forceinline__ float sspf(float z) {
  const float LN2 = 0.6931471805599453f;
  float t = __expf(z);
  float r = __logf(1.0f + t) - LN2;
  return (z > 15.0f) ? (z - LN2) : r;
}

// pk f16 atomic add (memory-side RMW, 2 cols per 4B op)
__device__ __forceinline__ void atomic_pk_f16(_Float16* p, h2 v) {
  asm volatile("global_atomic_pk_add_f16 %0, %1, off" ::"v"(p), "v"(v)
               : "memory");
}

// Pack B matrix [K][128] (row-major f32, K = nkb*32) into bf16 MFMA
// B-fragments in LDS; hot-loop read is a coalesced conflict-free ds_read_b128.
__device__ __forceinline__ void pack_bfrags(const float* __restrict__ w,
                                            short* __restrict__ dst, int nkb,
                                            int tid, int nthreads) {
  int total = 8 * nkb * 64;
  for (int i = tid; i < total; i += nthreads) {
    int L = i & 63;
    int f = i >> 6;
    int kb = f % nkb;
    int t = f / nkb;
    int col = t * 16 + (L & 15);
    int k0 = kb * 32 + ((L >> 4) << 3);
    bf8 vv;
#pragma unroll
    for (int j = 0; j < 8; ++j)
      vv[j] = (short)f2bf(w[(size_t)(k0 + j) * HDIM + col]);
    *(bf8*)(dst + (size_t)i * 8) = vv;
  }
}

// ---------------- kernel 1: v = bf16(x @ lin1_w + lin1_b) ----------------
__global__ __launch_bounds__(256, 2) void k_pre(const float* __restrict__ x,
                                                const float* __restrict__ w1,
                                                const float* __restrict__ b1,
                                                unsigned short* __restrict__ v) {
  __shared__ __attribute__((aligned(16))) short bfr[32 * 64 * 8];   // 32 KB
  __shared__ __attribute__((aligned(16))) short stg[4][16 * 136];   // 17 KB
  __shared__ float bias[HDIM];
  int tid = threadIdx.x;
  pack_bfrags(w1, bfr, 4, tid, 256);
  if (tid < HDIM) bias[tid] = b1[tid];
  __syncthreads();

  int wave = tid >> 6, L = tid & 63;
  int m = L & 15, q = L >> 4;
  short* sw = &stg[wave][0];
  int gw = (blockIdx.x * 256 + tid) >> 6;
  int nw = (gridDim.x * 256) >> 6;
  const int ntile = N_NODES / 16;
  for (int tile = gw; tile < ntile; tile += nw) {
    int row0 = tile << 4;
    const float* xr = x + (size_t)(row0 + m) * HDIM;
    bf8 a[4];
#pragma unroll
    for (int kb = 0; kb < 4; ++kb) {
      int k0 = kb * 32 + q * 8;
      f4 lo = *(const f4*)(xr + k0);
      f4 hi = *(const f4*)(xr + k0 + 4);
      bf8 t8;
#pragma unroll
      for (int j = 0; j < 4; ++j) {
        t8[j] = (short)f2bf(lo[j]);
        t8[4 + j] = (short)f2bf(hi[j]);
      }
      a[kb] = t8;
    }
    f4 acc[8];
#pragma unroll
    for (int t = 0; t < 8; ++t) acc[t] = (f4){0.f, 0.f, 0.f, 0.f};
#pragma unroll
    for (int kb = 0; kb < 4; ++kb)
#pragma unroll
      for (int t = 0; t < 8; ++t)
        acc[t] = __builtin_amdgcn_mfma_f32_16x16x32_bf16(
            a[kb], *(const bf8*)(bfr + ((t * 4 + kb) * 64 + L) * 8), acc[t], 0,
            0, 0);
    // stage C-tile (bf16) in LDS, then write out coalesced (16B/lane)
#pragma unroll
    for (int t = 0; t < 8; ++t) {
      int col = t * 16 + m;
      float bb = bias[col];
#pragma unroll
      for (int r = 0; r < 4; ++r)
        sw[(q * 4 + r) * 136 + col] = (short)f2bf(acc[t][r] + bb);
    }
#pragma unroll
    for (int j = 0; j < 4; ++j) {
      int row = j * 4 + (L >> 4);
      bf8 val = *(const bf8*)(sw + row * 136 + (L & 15) * 8);
      *(bf8*)(v + (size_t)(row0 + row) * HDIM + (L & 15) * 8) = val;
    }
  }
}

// ------- kernel 2: edge filter + gather + modulate + scatter-add -------
__global__ __launch_bounds__(256, 2) void k_edge(
    const float* __restrict__ ea, const float* __restrict__ ew,
    const float* __restrict__ cf1, const float* __restrict__ cf2,
    const float* __restrict__ cb2, const int* __restrict__ ei,
    const unsigned short* __restrict__ v, _Float16* __restrict__ agg) {
  __shared__ __attribute__((aligned(16))) short b1f[16 * 64 * 8];  // 16 KB
  __shared__ __attribute__((aligned(16))) short b2f[32 * 64 * 8];  // 32 KB
  __shared__ __attribute__((aligned(16))) short scr[4][16 * 136];  // 17 KB
  __shared__ float bias2[HDIM];
  int tid = threadIdx.x;
  pack_bfrags(cf1, b1f, 2, tid, 256);
  pack_bfrags(cf2, b2f, 4, tid, 256);
  if (tid < HDIM) bias2[tid] = cb2[tid];
  __syncthreads();

  // edge_index may arrive int64 (odd int32 words all zero) or int32.
  int stride64 = ((ei[1] | ei[3] | ei[5] | ei[7] | ei[9] | ei[11]) == 0) ? 2 : 1;

  int wave = tid >> 6, L = tid & 63;
  int m = L & 15, q = L >> 4;
  int modd = m & 1;
  short* wsc = &scr[wave][0];
  int gw = (blockIdx.x * 256 + tid) >> 6;
  int nw = (gridDim.x * 256) >> 6;
  const int ntile = NEDGE / 16;
  for (int tile = gw; tile < ntile; tile += nw) {
    int e0 = tile << 4;
    // ---- GEMM1: z1 = edge_attr @ cf1_w  (K = 64) ----
    const float* ar = ea + (size_t)(e0 + m) * ECH;
    bf8 a[2];
#pragma unroll
    for (int kb = 0; kb < 2; ++kb) {
      int k0 = kb * 32 + q * 8;
      f4 lo = *(const f4*)(ar + k0);
      f4 hi = *(const f4*)(ar + k0 + 4);
      bf8 t8;
#pragma unroll
      for (int j = 0; j < 4; ++j) {
        t8[j] = (short)f2bf(lo[j]);
        t8[4 + j] = (short)f2bf(hi[j]);
      }
      a[kb] = t8;
    }
    f4 acc[8];
#pragma unroll
    for (int t = 0; t < 8; ++t) acc[t] = (f4){0.f, 0.f, 0.f, 0.f};
#pragma unroll
    for (int kb = 0; kb < 2; ++kb)
#pragma unroll
      for (int t = 0; t < 8; ++t)
        acc[t] = __builtin_amdgcn_mfma_f32_16x16x32_bf16(
            a[kb], *(const bf8*)(b1f + ((t * 2 + kb) * 64 + L) * 8), acc[t], 0,
            0, 0);
    // W1 = ssp(z1) -> per-wave LDS scratch (C-layout write, padded stride)
#pragma unroll
    for (int t = 0; t < 8; ++t) {
      int col = t * 16 + m;
#pragma unroll
      for (int r = 0; r < 4; ++r)
        wsc[(q * 4 + r) * 136 + col] = (short)f2bf(sspf(acc[t][r]));
    }
    // ---- GEMM2: z2 = W1 @ cf2_w  (K = 128); A-frags from scratch ----
    bf8 a2[4];
#pragma unroll
    for (int kb = 0; kb < 4; ++kb)
      a2[kb] = *(const bf8*)(wsc + m * 136 + kb * 32 + q * 8);
#pragma unroll
    for (int t = 0; t < 8; ++t) acc[t] = (f4){0.f, 0.f, 0.f, 0.f};
#pragma unroll
    for (int kb = 0; kb < 4; ++kb)
#pragma unroll
      for (int t = 0; t < 8; ++t)
        acc[t] = __builtin_amdgcn_mfma_f32_16x16x32_bf16(
            a2[kb], *(const bf8*)(b2f + ((t * 4 + kb) * 64 + L) * 8), acc[t], 0,
            0, 0);
    // ---- epilogue: W2 = ssp(z2+b); msg = v[src]*W2*ew; pk-f16 atomics ----
#pragma unroll
    for (int r = 0; r < 4; ++r) {
      int erow = e0 + q * 4 + r;
      int srcn = ei[(size_t)erow * stride64];
      int dstn = ei[((size_t)NEDGE + erow) * stride64];
      float w_e = ew[erow];
      const unsigned short* vrow = v + (size_t)srcn * HDIM;
      _Float16* arow = agg + (size_t)dstn * HDIM;
#pragma unroll
      for (int t = 0; t < 8; t += 2) {
        float wv0 = sspf(acc[t][r] + bias2[t * 16 + m]) * w_e;
        float wv1 = sspf(acc[t + 1][r] + bias2[(t + 1) * 16 + m]) * w_e;
        // lane-pair exchange: even lane handles pair at t, odd at t+1
        float send = modd ? wv0 : wv1;
        float rcv = __shfl_xor(send, 1, 64);
        int basecol = modd ? ((t + 1) * 16 + m - 1) : (t * 16 + m);
        float lo = modd ? rcv : wv0;
        float hi = modd ? wv1 : rcv;
        unsigned vp = *(const unsigned*)(vrow + basecol);
        float msg0 = bf2f((unsigned short)(vp & 0xffffu)) * lo;
        float msg1 = bf2f((unsigned short)(vp >> 16)) * hi;
        h2 val;
        val[0] = (_Float16)msg0;
        val[1] = (_Float16)msg1;
        atomic_pk_f16(arow + basecol, val);
      }
    }
  }
}

// --- kernel 3: out = x + ssp(agg @ lin2 + b2) @ lin3 + b3 ---
__global__ __launch_bounds__(256, 1) void k_post(
    const _Float16* __restrict__ agg, const float* __restrict__ w2,
    const float* __restrict__ b2, const float* __restrict__ w3,
    const float* __restrict__ b3, const float* __restrict__ x,
    float* __restrict__ out) {
  __shared__ __attribute__((aligned(16))) short f2l[32 * 64 * 8];   // 32 KB
  __shared__ __attribute__((aligned(16))) short f3l[32 * 64 * 8];   // 32 KB
  __shared__ __attribute__((aligned(16))) unsigned char ustg[4][8448];  // 33 KB
  __shared__ float bias2[HDIM], bias3[HDIM];
  int tid = threadIdx.x;
  pack_bfrags(w2, f2l, 4, tid, 256);
  pack_bfrags(w3, f3l, 4, tid, 256);
  if (tid < HDIM) {
    bias2[tid] = b2[tid];
    bias3[tid] = b3[tid];
  }
  __syncthreads();

  int wave = tid >> 6, L = tid & 63;
  int m = L & 15, q = L >> 4;
  short* hsc = (short*)&ustg[wave][0];   // 16 x 136 bf16 (h transpose)
  float* osc = (float*)&ustg[wave][0];   // 16 x 132 f32 (out staging)
  int gw = (blockIdx.x * 256 + tid) >> 6;
  int nw = (gridDim.x * 256) >> 6;
  const int ntile = N_NODES / 16;
  for (int tile = gw; tile < ntile; tile += nw) {
    int row0 = tile << 4;
    const _Float16* gr = agg + (size_t)(row0 + m) * HDIM;
    bf8 a[4];
#pragma unroll
    for (int kb = 0; kb < 4; ++kb) {
      h8 hv = *(const h8*)(gr + kb * 32 + q * 8);
      bf8 t8;
#pragma unroll
      for (int j = 0; j < 8; ++j) t8[j] = (short)f2bf((float)hv[j]);
      a[kb] = t8;
    }
    f4 acc[8];
#pragma unroll
    for (int t = 0; t < 8; ++t) acc[t] = (f4){0.f, 0.f, 0.f, 0.f};
#pragma unroll
    for (int kb = 0; kb < 4; ++kb)
#pragma unroll
      for (int t = 0; t < 8; ++t)
        acc[t] = __builtin_amdgcn_mfma_f32_16x16x32_bf16(
            a[kb], *(const bf8*)(f2l + ((t * 4 + kb) * 64 + L) * 8), acc[t], 0,
            0, 0);
    // h = ssp(z + b2) -> scratch (bf16)
#pragma unroll
    for (int t = 0; t < 8; ++t) {
      int col = t * 16 + m;
      float bb = bias2[col];
#pragma unroll
      for (int r = 0; r < 4; ++r)
        hsc[(q * 4 + r) * 136 + col] = (short)f2bf(sspf(acc[t][r] + bb));
    }
    bf8 a2[4];
#pragma unroll
    for (int kb = 0; kb < 4; ++kb)
      a2[kb] = *(const bf8*)(hsc + m * 136 + kb * 32 + q * 8);
#pragma unroll
    for (int t = 0; t < 8; ++t) acc[t] = (f4){0.f, 0.f, 0.f, 0.f};
#pragma unroll
    for (int kb = 0; kb < 4; ++kb)
#pragma unroll
      for (int t = 0; t < 8; ++t)
        acc[t] = __builtin_amdgcn_mfma_f32_16x16x32_bf16(
            a2[kb], *(const bf8*)(f3l + ((t * 4 + kb) * 64 + L) * 8), acc[t], 0,
            0, 0);
    // stage z3 + b3 (f32) in LDS, then coalesced read-modify-write with x
#pragma unroll
    for (int t = 0; t < 8; ++t) {
      int col = t * 16 + m;
      float bb = bias3[col];
#pragma unroll
      for (int r = 0; r < 4; ++r)
        osc[(q * 4 + r) * 132 + col] = acc[t][r] + bb;
    }
#pragma unroll
    for (int j = 0; j < 8; ++j) {
      int row = j * 2 + (L >> 5);
      int col = (L & 31) * 4;
      f4 z = *(const f4*)(osc + row * 132 + col);
      f4 xv = *(const f4*)(x + (size_t)(row0 + row) * HDIM + col);
      f4 o;
#pragma unroll
      for (int c = 0; c < 4; ++c) o[c] = xv[c] + z[c];
      *(f4*)(out + (size_t)(row0 + row) * HDIM + col) = o;
    }
  }
}

extern "C" void kernel_launch(void* const* d_in, const int* in_sizes, int n_in,
                              void* d_out, int out_size, void* d_ws,
                              size_t ws_size, hipStream_t stream) {
  const float* x = (const float*)d_in[0];
  const float* ea = (const float*)d_in[1];
  const float* ew = (const float*)d_in[2];
  const float* l1w = (const float*)d_in[3];
  const float* l1b = (const float*)d_in[4];
  const float* c1w = (const float*)d_in[5];
  const float* c2w = (const float*)d_in[6];
  const float* c2b = (const float*)d_in[7];
  const float* l2w = (const float*)d_in[8];
  const float* l2b = (const float*)d_in[9];
  const float* l3w = (const float*)d_in[10];
  const float* l3b = (const float*)d_in[11];
  const int* ei = (const int*)d_in[12];
  float* out = (float*)d_out;

  unsigned short* v = (unsigned short*)d_ws;              // [N,128] bf16, 25.6 MB
  _Float16* agg = (_Float16*)(v + (size_t)N_NODES * HDIM);  // [N,128] f16, 25.6 MB

  hipMemsetAsync(agg, 0, (size_t)N_NODES * HDIM * sizeof(_Float16), stream);
  k_pre<<<512, 256, 0, stream>>>(x, l1w, l1b, v);
  k_edge<<<512, 256, 0, stream>>>(ea, ew, c1w, c2w, c2b, ei, v, agg);
  k_post<<<256, 256, 0, stream>>>(agg, l2w, l2b, l3w, l3b, x, out);
}